// Round 15
// baseline (165.257 us; speedup 1.0000x reference)
//
#include <hip/hip_runtime.h>
#include <hip/hip_bf16.h>

#define NN 16384
#define DD 256

typedef unsigned short u16;
typedef unsigned int u32;
typedef unsigned char u8;
typedef long i64;
typedef __attribute__((ext_vector_type(4))) float f32x4;
typedef __attribute__((ext_vector_type(4))) int i32x4;
typedef __attribute__((ext_vector_type(8))) int i32x8;

// ---------- kernel 1: fp8 e4m3 convert, LDS-transposed, all-coalesced ----------
// (verbatim from R6 -- measured clean, absmax 0.)
// A8 and B8 share ONE fragment-linear layout:
//   addr = pn<<15 | k2<<14 | r8<<11 | jj<<10 | qq<<8 | mm<<4 | u
//   holding fp8 of row (pn*128 + r8*16 + mm), kbyte (k2*128 + qq*32 + jj*16 + u).
__global__ __launch_bounds__(256) void prep_kernel(
        const float* __restrict__ img, const float* __restrict__ txt,
        u8* __restrict__ A8, u8* __restrict__ B8,
        float* __restrict__ zbuf /* s_row..s_col 32768 f */,
        float* __restrict__ out) {
    __shared__ u32 sA[16 * 65 + 8];
    __shared__ u32 sB[16 * 65 + 8];
    const int t = threadIdx.x, bi = blockIdx.x;            // bi = 16-row window
    const float4* ib = (const float4*)img + ((size_t)bi << 10);
    const float4* tb = (const float4*)txt + ((size_t)bi << 10);
    const float S = 1.44269504088896f;                     // log2(e) folded into A
    #pragma unroll
    for (int k = 0; k < 4; ++k) {
        const int idx = (k << 8) + t;                      // 0..1023 float4s
        const int row = idx >> 6, col = idx & 63;          // row 0..15, col 0..63
        float4 va = ib[idx];
        int pa = __builtin_amdgcn_cvt_pk_fp8_f32(va.x * S, va.y * S, 0, false);
        pa     = __builtin_amdgcn_cvt_pk_fp8_f32(va.z * S, va.w * S, pa, true);
        sA[row * 65 + col] = (u32)pa;
        float4 vb = tb[idx];
        int pb = __builtin_amdgcn_cvt_pk_fp8_f32(vb.x, vb.y, 0, false);
        pb     = __builtin_amdgcn_cvt_pk_fp8_f32(vb.z, vb.w, pb, true);
        sB[row * 65 + col] = (u32)pb;
    }
    __syncthreads();
    const int w = t >> 6, l = t & 63;
    const int k2 = w >> 1, jj = w & 1, qq = l >> 4, mm = l & 15;
    const int wb = mm * 65 + (k2 << 5) + (qq << 3) + (jj << 2);
    i32x4 oa = { (int)sA[wb], (int)sA[wb + 1], (int)sA[wb + 2], (int)sA[wb + 3] };
    i32x4 ob = { (int)sB[wb], (int)sB[wb + 1], (int)sB[wb + 2], (int)sB[wb + 3] };
    const size_t dst = ((size_t)(bi >> 3) << 15) + (k2 << 14) + ((size_t)(bi & 7) << 11)
                     + (jj << 10) + (qq << 8) + (mm << 4);
    *(i32x4*)(A8 + dst) = oa;
    *(i32x4*)(B8 + dst) = ob;
    const int gid = (bi << 8) + t;
    if (gid < 32768) zbuf[gid] = 0.0f;
    if (gid == 0) out[0] = 0.0f;
}

// ---------- kernel 2: PRODUCER/CONSUMER wave-specialized GEMM+LSE ----------
// vs R8/R11/R14 (gemm ~78 us plateau, MfmaUtil 36 + VALUBusy 44 = 80%):
// each wave's serial [MFMA]->[epilogue] chain + only 2 waves/SIMD leaves the
// pipes SERIALIZED; register pipelining spills (R7/R9/R10), emission pinning
// hurts (R13), skew neutral (R14). Fix BY CONSTRUCTION (m114: MFMA-wave +
// VALU-wave on one SIMD co-schedule at time=max): 512-thread blocks, waves
// 0-3 = PRODUCERS (loads + 16 MFMA/half + ds_write handoff; zero epilogue),
// waves 4-7 = CONSUMERS (ds_read + exp2 + row/col sums + diag + atomics;
// zero MFMA). Each SIMD holds exactly 1 producer + 1 consumer.
// Handoff: 32KB LDS per half (4 prod waves x 64 lanes x 32 f), two buffers
// by half-parity (static indexing), ONE barrier per half-phase; both paths
// execute exactly 128 barriers (audited interval-by-interval). lane*16B
// b128 handoff is bank-conflict-free; consumer reads its own lane's data.
// Grid 256 (1 block/CU, regs limit), 64 col tiles/block, stagger (jt+bi)&63.
// Budget: MFMA pipe 29.5 us/SIMD, consumer ~29 us -> wall ~ max + sync.
// Tripwires: WRITE 17.47 MB, FETCH ~18.5 MB, VGPR <= ~200, conflicts ~0.
__global__ __launch_bounds__(512, 2) void gemm_lse_kernel(
        const u8* __restrict__ A8, const u8* __restrict__ B8,
        float* __restrict__ s_row, float* __restrict__ s_col,
        float* __restrict__ diag) {
    __shared__ float hbuf0[8192];   // 32 KB: h=0 handoff [pw][rb*2+cb][lane][4]
    __shared__ float hbuf1[8192];   // 32 KB: h=1 handoff

    const int t = threadIdx.x;
    const int lane = t & 63;
    const int w = t >> 6;              // 0..7
    const int pw = w & 3;              // producer/consumer pair id
    const int wr = pw >> 1, wc = pw & 1;
    const int q = lane >> 4, m = lane & 15;
    const int bi = blockIdx.x & 127;
    const int jg = blockIdx.x >> 7;    // 0..1 (64 tiles each)
    const int row0 = bi << 7;

    if (w < 4) {
        // ======================= PRODUCER =======================
        const u8* Aw = A8 + ((size_t)bi << 15) + ((size_t)lane << 4);
        i32x8 areg[2][4];
        #pragma unroll
        for (int k2 = 0; k2 < 2; ++k2)
            #pragma unroll
            for (int rb = 0; rb < 4; ++rb) {
                const u8* p = Aw + (k2 << 14) + (((wr << 2) + rb) << 11);
                i32x4 lo = *(const i32x4*)(p);
                i32x4 hi = *(const i32x4*)(p + 1024);
                areg[k2][rb] = __builtin_shufflevector(lo, hi, 0, 1, 2, 3, 4, 5, 6, 7);
            }
        const u8* Bw = B8 + (wc << 13) + ((size_t)lane << 4);
        i32x8 bfX[4], bfY[4];
        auto load_half = [&](i32x8 (&bf)[4], int jt_, int h) {
            const int ct = (jg << 6) | ((jt_ + bi) & 63);
            const u8* p = Bw + ((size_t)ct << 15) + (h << 12);
            #pragma unroll
            for (int k2 = 0; k2 < 2; ++k2) {
                const u8* pp = p + (k2 << 14);
                i32x4 lo0 = *(const i32x4*)(pp);
                i32x4 hi0 = *(const i32x4*)(pp + 1024);
                bf[k2 * 2 + 0] = __builtin_shufflevector(lo0, hi0, 0, 1, 2, 3, 4, 5, 6, 7);
                i32x4 lo1 = *(const i32x4*)(pp + 2048);
                i32x4 hi1 = *(const i32x4*)(pp + 3072);
                bf[k2 * 2 + 1] = __builtin_shufflevector(lo1, hi1, 0, 1, 2, 3, 4, 5, 6, 7);
            }
        };
        auto mfma_half = [&](f32x4 (&acc)[4][2], i32x8 (&bf)[4]) {
            const f32x4 cinit = {-144.f, -144.f, -144.f, -144.f};
            #pragma unroll
            for (int rb = 0; rb < 4; ++rb) {
                acc[rb][0] = __builtin_amdgcn_mfma_scale_f32_16x16x128_f8f6f4(
                    areg[0][rb], bf[0], cinit, 0, 0, 0, 127, 0, 127);
                acc[rb][1] = __builtin_amdgcn_mfma_scale_f32_16x16x128_f8f6f4(
                    areg[0][rb], bf[1], cinit, 0, 0, 0, 127, 0, 127);
            }
            #pragma unroll
            for (int rb = 0; rb < 4; ++rb) {
                acc[rb][0] = __builtin_amdgcn_mfma_scale_f32_16x16x128_f8f6f4(
                    areg[1][rb], bf[2], acc[rb][0], 0, 0, 0, 127, 0, 127);
                acc[rb][1] = __builtin_amdgcn_mfma_scale_f32_16x16x128_f8f6f4(
                    areg[1][rb], bf[3], acc[rb][1], 0, 0, 0, 127, 0, 127);
            }
        };
        float* myb0 = hbuf0 + (pw << 11) + (lane << 2);
        float* myb1 = hbuf1 + (pw << 11) + (lane << 2);
        f32x4 acc[4][2];

        load_half(bfX, 0, 0);                  // exposed once (prologue)
        #pragma unroll 1
        for (int jt = 0; jt < 64; ++jt) {
            // phase (jt,0): compute h0 from bfX, prefetch h1 into bfY
            load_half(bfY, jt, 1);
            mfma_half(acc, bfX);
            #pragma unroll
            for (int rb = 0; rb < 4; ++rb)
                #pragma unroll
                for (int cb = 0; cb < 2; ++cb)
                    *(f32x4*)(myb0 + (((rb << 1) | cb) << 8)) = acc[rb][cb];
            __syncthreads();
            // phase (jt,1): compute h1 from bfY, prefetch next h0 into bfX
            if (jt < 63) load_half(bfX, jt + 1, 0);
            mfma_half(acc, bfY);
            #pragma unroll
            for (int rb = 0; rb < 4; ++rb)
                #pragma unroll
                for (int cb = 0; cb < 2; ++cb)
                    *(f32x4*)(myb1 + (((rb << 1) | cb) << 8)) = acc[rb][cb];
            __syncthreads();
        }
    } else {
        // ======================= CONSUMER =======================
        const f32x4 fzero = {0.f, 0.f, 0.f, 0.f};
        f32x4 rp[4] = {fzero, fzero, fzero, fzero};
        float cpartT = 0.0f;
        const float* myr0 = hbuf0 + (pw << 11) + (lane << 2);
        const float* myr1 = hbuf1 + (pw << 11) + (lane << 2);

        auto consume = [&](const float* src, int jt_, int h) {
            const int ct = (jg << 6) | ((jt_ + bi) & 63);
            f32x4 ev[4][2];
            #pragma unroll
            for (int rb = 0; rb < 4; ++rb)
                #pragma unroll
                for (int cb = 0; cb < 2; ++cb)
                    ev[rb][cb] = *(const f32x4*)(src + (((rb << 1) | cb) << 8));
            if (bi == ct && wr == wc) {      // diag from raw (biased) values
                #pragma unroll
                for (int rb = 0; rb < 4; ++rb)
                    if ((rb >> 1) == h) {
                        #pragma unroll
                        for (int r = 0; r < 4; ++r)
                            if (m == ((q << 2) | r))
                                diag[row0 + (wr << 6) + (rb << 4) + m] = ev[rb][rb & 1][r];
                    }
            }
            #pragma unroll
            for (int rb = 0; rb < 4; ++rb)
                #pragma unroll
                for (int cb = 0; cb < 2; ++cb)
                    #pragma unroll
                    for (int r = 0; r < 4; ++r)
                        ev[rb][cb][r] = __builtin_amdgcn_exp2f(ev[rb][cb][r]);
            #pragma unroll
            for (int rb = 0; rb < 4; ++rb)
                rp[rb] += ev[rb][0] + ev[rb][1];
            #pragma unroll
            for (int cb = 0; cb < 2; ++cb) {
                f32x4 s = (ev[0][cb] + ev[1][cb]) + (ev[2][cb] + ev[3][cb]);
                float v = (s[0] + s[1]) + (s[2] + s[3]);
                v += __shfl_xor(v, 16, 64);
                v += __shfl_xor(v, 32, 64);
                if (q == ((h << 1) | cb)) cpartT = v;
            }
            if (h == 1) {
                const int col0 = ct << 7;
                atomicAdd(&s_col[col0 + (wc << 6) + (q << 4) + m], cpartT);
            }
        };

        __syncthreads();                       // interval (0,0): nothing yet
        #pragma unroll 1
        for (int jt = 0; jt < 64; ++jt) {
            consume(myr0, jt, 0);              // interval (jt,1): h0 data
            __syncthreads();
            if (jt < 63) {
                consume(myr1, jt, 1);          // interval (jt+1,0): h1 data
                __syncthreads();
            }
        }
        consume(myr1, 63, 1);                  // after final barrier

        // ---- row reduction (consumer waves only) ----
        float rout = 0.0f;
        #pragma unroll
        for (int rb = 0; rb < 4; ++rb)
            #pragma unroll
            for (int r = 0; r < 4; ++r) {
                float v = rp[rb][r];
                v += __shfl_xor(v, 1, 16);
                v += __shfl_xor(v, 2, 16);
                v += __shfl_xor(v, 4, 16);
                v += __shfl_xor(v, 8, 16);
                if (m == ((rb << 2) | r)) rout = v;
            }
        atomicAdd(&s_row[row0 + (wr << 6) + ((m >> 2) << 4) + (q << 2) + (m & 3)], rout);
    }
}

// ---------- kernel 3: final reduce (64 blocks, 256 rows each) ----------
// diag is biased by -144; the +144 LSE un-bias cancels it exactly.
__global__ void final_kernel(const float* __restrict__ s_row, const float* __restrict__ s_col,
                             const float* __restrict__ diag, float* __restrict__ out) {
    __shared__ double red[256];
    int t = threadIdx.x;
    int i = blockIdx.x * 256 + t;
    double p = 0.5 * (double)(log2f(s_row[i]) + log2f(s_col[i])) - (double)diag[i];
    red[t] = p;
    __syncthreads();
    for (int s = 128; s > 0; s >>= 1) {
        if (t < s) red[t] += red[t + s];
        __syncthreads();
    }
    if (t == 0) atomicAdd(out, (float)(red[0] * 0.6931471805599453 / (double)NN));
}

// ---------- launch ----------
extern "C" void kernel_launch(void* const* d_in, const int* in_sizes, int n_in,
                              void* d_out, int out_size, void* d_ws, size_t ws_size,
                              hipStream_t stream) {
    const float* img = (const float*)d_in[0];
    const float* txt = (const float*)d_in[1];
    char* ws = (char*)d_ws;
    u8*    A8    = (u8*)ws;                                // 4 MB
    u8*    B8    = (u8*)(ws + 4194304);                    // 4 MB
    float* s_row = (float*)(ws + 8388608);                 // 64 KB
    float* s_col = (float*)(ws + 8388608 + 65536);         // 64 KB
    float* diag  = (float*)(ws + 8388608 + 131072);        // 64 KB
    float* out   = (float*)d_out;

    prep_kernel<<<1024, 256, 0, stream>>>(img, txt, A8, B8, s_row, out);
    gemm_lse_kernel<<<256, 512, 0, stream>>>(A8, B8, s_row, s_col, diag);
    final_kernel<<<64, 256, 0, stream>>>(s_row, s_col, diag, out);
}